// Round 12
// baseline (240.722 us; speedup 1.0000x reference)
//
#include <hip/hip_runtime.h>

// Problem constants (B=4, C=256, H=W=56, heads=8)
#define NUM_G 8
#define HD    32
#define LSP   3136            // 56*56 = 49*64 exactly
#define BG    32
#define TPB   256
#define LOG2E 1.4426950408889634f

typedef short bf16x8 __attribute__((ext_vector_type(8)));
typedef short short4v __attribute__((ext_vector_type(4)));
typedef float f32x4  __attribute__((ext_vector_type(4)));
typedef unsigned uint2v __attribute__((ext_vector_type(2)));
typedef unsigned uint4v __attribute__((ext_vector_type(4)));

union B8 { bf16x8 h; uint4v u; };
union U8 { bf16x8 h; uint2v u[2]; };

extern "C" __device__ float __ocml_native_exp2_f32(float);
__device__ __forceinline__ float fast_exp2(float x) {
#if __has_builtin(__builtin_amdgcn_exp2f)
    return __builtin_amdgcn_exp2f(x);
#else
    return __ocml_native_exp2_f32(x);     // lowers to v_exp_f32
#endif
}

__device__ __forceinline__ unsigned pk_bf16(float a, float b) {
#if __has_builtin(__builtin_amdgcn_cvt_pk_bf16_f32)
    typedef __bf16 bf16x2_t __attribute__((ext_vector_type(2)));
    bf16x2_t r = __builtin_amdgcn_cvt_pk_bf16_f32(a, b);
    unsigned u; __builtin_memcpy(&u, &r, 4); return u;
#else
    unsigned ua = __float_as_uint(a); ua += 0x7FFFu + ((ua >> 16) & 1u);
    unsigned ub = __float_as_uint(b); ub += 0x7FFFu + ((ub >> 16) & 1u);
    return (ua >> 16) | (ub & 0xFFFF0000u);
#endif
}

__device__ __forceinline__ short f2bf(float f) {
    unsigned u = __float_as_uint(f);
    u += 0x7FFFu + ((u >> 16) & 1u);
    return (short)(u >> 16);
}

__device__ __forceinline__ float bf2f(short s) {
    return __uint_as_float(((unsigned)(unsigned short)s) << 16);
}

// ---------------- Kernel 1: grouped 1x1 conv via MFMA (R11 form, 1568 blocks) ----------------
__global__ __launch_bounds__(TPB, 4) void qkv_mfma(
    const float* __restrict__ x,
    const float* __restrict__ Wq, const float* __restrict__ bq,
    const float* __restrict__ Wk, const float* __restrict__ bk,
    const float* __restrict__ Wv, const float* __restrict__ bv,
    short* __restrict__ qt, short* __restrict__ kt, short* __restrict__ v)
{
    const int bg = blockIdx.y, gh = bg & (NUM_G - 1);
    const int lane = threadIdx.x & 63, w = threadIdx.x >> 6;
    const int m = lane & 15, g = lane >> 4;

    const float* xb = x + (size_t)bg * HD * LSP;
    short* qtb = qt + (size_t)bg * LSP * HD;
    short* ktb = kt + (size_t)bg * LSP * HD;
    short* vb  = v  + (size_t)bg * HD * LSP;

    B8 wqf[2], wkf[2], wvf[2];
    float bqv[2], bkv[2], bvv[2][4];
#pragma unroll
    for (int h = 0; h < 2; ++h) {
        const int o = 16 * h + m;
        const float* wqp = Wq + (size_t)(gh * HD + o) * HD + 8 * g;
        const float* wkp = Wk + (size_t)(gh * HD + o) * HD + 8 * g;
        const float* wvp = Wv + (size_t)(gh * HD + o) * HD + 8 * g;
#pragma unroll
        for (int p = 0; p < 4; ++p) {
            wqf[h].u[p] = pk_bf16(wqp[2*p] * LOG2E, wqp[2*p+1] * LOG2E);
            wkf[h].u[p] = pk_bf16(wkp[2*p],         wkp[2*p+1]);
            wvf[h].u[p] = pk_bf16(wvp[2*p],         wvp[2*p+1]);
        }
        bqv[h] = bq[gh * HD + o] * LOG2E;
        bkv[h] = bk[gh * HD + o];
#pragma unroll
        for (int r = 0; r < 4; ++r)
            bvv[h][r] = bv[gh * HD + 16 * h + 4 * g + r];
    }

    const int lc = blockIdx.x * 64 + 16 * w;
    const int lrow = lc + m;
    const f32x4 zero = {0.f, 0.f, 0.f, 0.f};
    B8 xf;
#pragma unroll
    for (int p = 0; p < 4; ++p) {
        const float a0 = xb[(size_t)(8*g + 2*p)     * LSP + lrow];
        const float a1 = xb[(size_t)(8*g + 2*p + 1) * LSP + lrow];
        xf.u[p] = pk_bf16(a0, a1);
    }
#pragma unroll
    for (int h = 0; h < 2; ++h) {
        f32x4 cq = __builtin_amdgcn_mfma_f32_16x16x32_bf16(xf.h, wqf[h].h, zero, 0, 0, 0);
        f32x4 ck = __builtin_amdgcn_mfma_f32_16x16x32_bf16(xf.h, wkf[h].h, zero, 0, 0, 0);
        f32x4 cv = __builtin_amdgcn_mfma_f32_16x16x32_bf16(wvf[h].h, xf.h, zero, 0, 0, 0);
#pragma unroll
        for (int r = 0; r < 4; ++r) {
            const int lr = lc + 4 * g + r;
            qtb[(size_t)lr * HD + 16 * h + m] = f2bf(cq[r] + bqv[h]);
            ktb[(size_t)lr * HD + 16 * h + m] = f2bf(ck[r] + bkv[h]);
            vb[(size_t)(16 * h + 4 * g + r) * LSP + lc + m] = f2bf(cv[r] + bvv[h][r]);
        }
    }
}

// ---------------- Kernel 2: Z over 64-j block; v *= 1/Z in-place (R9 form) ----------------
__global__ __launch_bounds__(TPB, 6) void z_mfma(
    const short* __restrict__ qt, const short* __restrict__ kt,
    short* __restrict__ v)
{
    const int bg = blockIdx.y;
    const int jb = blockIdx.x * 64;
    const int t = threadIdx.x;
    const int lane = t & 63, w = t >> 6, m = lane & 15, g = lane >> 4;

    const short* qtb = qt + (size_t)bg * LSP * HD;
    const short* ktb = kt + (size_t)bg * LSP * HD;
    short* vb = v + (size_t)bg * HD * LSP;

    bf16x8 aq[4];
#pragma unroll
    for (int jq = 0; jq < 4; ++jq)
        aq[jq] = *(const bf16x8*)(qtb + (size_t)(jb + 16 * jq + m) * HD + 8 * g);

    f32x4 zacc[4];
#pragma unroll
    for (int jq = 0; jq < 4; ++jq) zacc[jq] = (f32x4){0.f, 0.f, 0.f, 0.f};

    const f32x4 zero = {0.f, 0.f, 0.f, 0.f};
    for (int it = 0; it < 49; ++it) {
        const bf16x8 bkc = *(const bf16x8*)(ktb + (size_t)(it * 64 + 16 * w + m) * HD + 8 * g);
#pragma unroll
        for (int jq = 0; jq < 4; ++jq) {
            f32x4 c = __builtin_amdgcn_mfma_f32_16x16x32_bf16(aq[jq], bkc, zero, 0, 0, 0);
#pragma unroll
            for (int r = 0; r < 4; ++r) zacc[jq][r] += fast_exp2(c[r]);
        }
    }

    __shared__ float zl[64];
    if (t < 64) zl[t] = 0.f;
    __syncthreads();
#pragma unroll
    for (int jq = 0; jq < 4; ++jq) {
#pragma unroll
        for (int r = 0; r < 4; ++r) {
            float s = zacc[jq][r];
            s += __shfl_xor(s, 1); s += __shfl_xor(s, 2);
            s += __shfl_xor(s, 4); s += __shfl_xor(s, 8);
            if (m == 0) atomicAdd(&zl[16 * jq + 4 * g + r], s);
        }
    }
    __syncthreads();

    const int d0 = t >> 3;
    const int jl = (t & 7) * 8;
    float rzv[8];
#pragma unroll
    for (int e = 0; e < 8; ++e) rzv[e] = 1.0f / zl[jl + e];
    short* vp = vb + (size_t)d0 * LSP + jb + jl;
    bf16x8 vv = *(bf16x8*)vp;
    B8 o;
#pragma unroll
    for (int p = 0; p < 4; ++p)
        o.u[p] = pk_bf16(bf2f(vv[2*p]) * rzv[2*p], bf2f(vv[2*p+1]) * rzv[2*p+1]);
    *(bf16x8*)vp = o.h;
}

// ---------------- Kernel 3: out — 32 k-cols/block, grid 98x32 = 3136 blocks (~8 res/CU) ----------------
// R10 form + THE FIX: __syncthreads() between the jt-loop's unsigned* LDS reads and the
// epilogue's float* stores to the same region (TBAA lets the compiler reorder otherwise — R10 bug).
__global__ __launch_bounds__(TPB, 4) void out_mfma(
    const short* __restrict__ qt, const short* __restrict__ kt,
    const short* __restrict__ v,
    const float* __restrict__ x, float* __restrict__ out)
{
    const int bg = blockIdx.y;
    const int k0 = blockIdx.x * 32;
    const int lane = threadIdx.x & 63, w = threadIdx.x >> 6;
    const int m = lane & 15, g = lane >> 4;

    const short* qtb = qt + (size_t)bg * LSP * HD;
    const short* ktb = kt + (size_t)bg * LSP * HD;
    const short* vb  = v  + (size_t)bg * HD * LSP;

    bf16x8 bk[2];
#pragma unroll
    for (int ks = 0; ks < 2; ++ks)
        bk[ks] = *(const bf16x8*)(ktb + (size_t)(k0 + 16 * ks + m) * HD + 8 * g);

    __shared__ unsigned lds[4096];          // 16KB: loop [w][ks][512]; epilogue float[4][1024]
    unsigned* pw = lds + w * 1024;
    const int t2 = 2 * m;
    const int cb = m * 32;

    const f32x4 zero = {0.f, 0.f, 0.f, 0.f};
    f32x4 acc[2][2];
    acc[0][0] = zero; acc[0][1] = zero; acc[1][0] = zero; acc[1][1] = zero;

    for (int jt = w; jt < 49; jt += 4) {
        const int j0 = jt * 64;

        const bf16x8 av0 = *(const bf16x8*)(vb + (size_t)m        * LSP + j0      + 8 * g);
        const bf16x8 av1 = *(const bf16x8*)(vb + (size_t)m        * LSP + j0 + 32 + 8 * g);
        const bf16x8 av2 = *(const bf16x8*)(vb + (size_t)(16 + m) * LSP + j0      + 8 * g);
        const bf16x8 av3 = *(const bf16x8*)(vb + (size_t)(16 + m) * LSP + j0 + 32 + 8 * g);

        bf16x8 aq[4];
#pragma unroll
        for (int jq = 0; jq < 4; ++jq)
            aq[jq] = *(const bf16x8*)(qtb + (size_t)(j0 + 16 * jq + m) * HD + 8 * g);

#pragma unroll
        for (int ks = 0; ks < 2; ++ks) {
#pragma unroll
            for (int jq = 0; jq < 4; ++jq) {
                const f32x4 e = __builtin_amdgcn_mfma_f32_16x16x32_bf16(aq[jq], bk[ks], zero, 0, 0, 0);
                uint2v w0;
                w0[0] = pk_bf16(fast_exp2(e[0]), fast_exp2(e[1]));
                w0[1] = pk_bf16(fast_exp2(e[2]), fast_exp2(e[3]));
                *(uint2v*)(pw + ks * 512 + cb + ((8 * jq + 2 * g) ^ t2)) = w0;
            }
        }

        const int blo0 = (4 * g)          ^ t2;
        const int blo1 = (4 * g + 2)      ^ t2;
        const int bhi0 = (16 + 4 * g)     ^ t2;
        const int bhi1 = (16 + 4 * g + 2) ^ t2;
#pragma unroll
        for (int ks = 0; ks < 2; ++ks) {
            U8 bplo, bphi;
            bplo.u[0] = *(uint2v*)(pw + ks * 512 + cb + blo0);
            bplo.u[1] = *(uint2v*)(pw + ks * 512 + cb + blo1);
            bphi.u[0] = *(uint2v*)(pw + ks * 512 + cb + bhi0);
            bphi.u[1] = *(uint2v*)(pw + ks * 512 + cb + bhi1);
            acc[ks][0] = __builtin_amdgcn_mfma_f32_16x16x32_bf16(av0, bplo.h, acc[ks][0], 0, 0, 0);
            acc[ks][0] = __builtin_amdgcn_mfma_f32_16x16x32_bf16(av1, bphi.h, acc[ks][0], 0, 0, 0);
            acc[ks][1] = __builtin_amdgcn_mfma_f32_16x16x32_bf16(av2, bplo.h, acc[ks][1], 0, 0, 0);
            acc[ks][1] = __builtin_amdgcn_mfma_f32_16x16x32_bf16(av3, bphi.h, acc[ks][1], 0, 0, 0);
        }
    }

    // ---- THE FIX: barrier orders (and fences) the P reads above vs the float overwrite below ----
    __syncthreads();

    float* fl = (float*)lds;
#pragma unroll
    for (int ks = 0; ks < 2; ++ks)
#pragma unroll
        for (int ds = 0; ds < 2; ++ds)
#pragma unroll
            for (int r = 0; r < 4; ++r) {
                const int d = 16 * ds + 4 * g + r;
                fl[w * 1024 + d * 32 + 16 * ks + m] = acc[ks][ds][r];
            }
    __syncthreads();

    const int t = threadIdx.x;
    const int d = t >> 3;               // 0..31
    const int kloc = (t & 7) * 4;       // 0..28
    f32x4 sv = *(f32x4*)(fl + d * 32 + kloc);
#pragma unroll
    for (int wi = 1; wi < 4; ++wi) {
        const f32x4 a = *(f32x4*)(fl + wi * 1024 + d * 32 + kloc);
#pragma unroll
        for (int r = 0; r < 4; ++r) sv[r] += a[r];
    }
    const size_t idx = (size_t)bg * HD * LSP + (size_t)d * LSP + k0 + kloc;
    const f32x4 xv = *(const f32x4*)(x + idx);
#pragma unroll
    for (int r = 0; r < 4; ++r) sv[r] += xv[r];
    *(f32x4*)(out + idx) = sv;
}

extern "C" void kernel_launch(void* const* d_in, const int* in_sizes, int n_in,
                              void* d_out, int out_size, void* d_ws, size_t ws_size,
                              hipStream_t stream) {
    const float* x  = (const float*)d_in[0];
    const float* Wq = (const float*)d_in[1];
    const float* bq = (const float*)d_in[2];
    const float* Wk = (const float*)d_in[3];
    const float* bk = (const float*)d_in[4];
    const float* Wv = (const float*)d_in[5];
    const float* bv = (const float*)d_in[6];
    float* out = (float*)d_out;

    const size_t QSZ = (size_t)BG * HD * LSP;
    short* qt = (short*)d_ws;
    short* kt = qt + QSZ;
    short* v  = kt + QSZ;

    qkv_mfma<<<dim3(49, BG), TPB, 0, stream>>>(x, Wq, bq, Wk, bk, Wv, bv, qt, kt, v);
    z_mfma  <<<dim3(49, BG), TPB, 0, stream>>>(qt, kt, v);
    out_mfma<<<dim3(98, BG), TPB, 0, stream>>>(qt, kt, v, x, out);
}

// Round 13
// 204.906 us; speedup vs baseline: 1.1748x; 1.1748x over previous
//
#include <hip/hip_runtime.h>

// Problem constants (B=4, C=256, H=W=56, heads=8)
#define NUM_G 8
#define HD    32
#define LSP   3136            // 56*56 = 49*64 exactly
#define BG    32
#define LOG2E 1.4426950408889634f

typedef short bf16x8 __attribute__((ext_vector_type(8)));
typedef short short4v __attribute__((ext_vector_type(4)));
typedef float f32x4  __attribute__((ext_vector_type(4)));
typedef unsigned uint2v __attribute__((ext_vector_type(2)));
typedef unsigned uint4v __attribute__((ext_vector_type(4)));

union B8 { bf16x8 h; uint4v u; };
union U8 { bf16x8 h; uint2v u[2]; };
union U4 { short4v h; unsigned u[2]; };

extern "C" __device__ float __ocml_native_exp2_f32(float);
__device__ __forceinline__ float fast_exp2(float x) {
#if __has_builtin(__builtin_amdgcn_exp2f)
    return __builtin_amdgcn_exp2f(x);
#else
    return __ocml_native_exp2_f32(x);     // lowers to v_exp_f32
#endif
}

__device__ __forceinline__ unsigned pk_bf16(float a, float b) {
#if __has_builtin(__builtin_amdgcn_cvt_pk_bf16_f32)
    typedef __bf16 bf16x2_t __attribute__((ext_vector_type(2)));
    bf16x2_t r = __builtin_amdgcn_cvt_pk_bf16_f32(a, b);
    unsigned u; __builtin_memcpy(&u, &r, 4); return u;
#else
    unsigned ua = __float_as_uint(a); ua += 0x7FFFu + ((ua >> 16) & 1u);
    unsigned ub = __float_as_uint(b); ub += 0x7FFFu + ((ub >> 16) & 1u);
    return (ua >> 16) | (ub & 0xFFFF0000u);
#endif
}

__device__ __forceinline__ short f2bf(float f) {
    unsigned u = __float_as_uint(f);
    u += 0x7FFFu + ((u >> 16) & 1u);
    return (short)(u >> 16);
}

__device__ __forceinline__ float bf2f(short s) {
    return __uint_as_float(((unsigned)(unsigned short)s) << 16);
}

// ---------------- Kernel 1: grouped 1x1 conv via MFMA (R11 form, 1568 blocks of 256) ----------------
__global__ __launch_bounds__(256, 4) void qkv_mfma(
    const float* __restrict__ x,
    const float* __restrict__ Wq, const float* __restrict__ bq,
    const float* __restrict__ Wk, const float* __restrict__ bk,
    const float* __restrict__ Wv, const float* __restrict__ bv,
    short* __restrict__ qt, short* __restrict__ kt, short* __restrict__ v)
{
    const int bg = blockIdx.y, gh = bg & (NUM_G - 1);
    const int lane = threadIdx.x & 63, w = threadIdx.x >> 6;
    const int m = lane & 15, g = lane >> 4;

    const float* xb = x + (size_t)bg * HD * LSP;
    short* qtb = qt + (size_t)bg * LSP * HD;
    short* ktb = kt + (size_t)bg * LSP * HD;
    short* vb  = v  + (size_t)bg * HD * LSP;

    B8 wqf[2], wkf[2], wvf[2];
    float bqv[2], bkv[2], bvv[2][4];
#pragma unroll
    for (int h = 0; h < 2; ++h) {
        const int o = 16 * h + m;
        const float* wqp = Wq + (size_t)(gh * HD + o) * HD + 8 * g;
        const float* wkp = Wk + (size_t)(gh * HD + o) * HD + 8 * g;
        const float* wvp = Wv + (size_t)(gh * HD + o) * HD + 8 * g;
#pragma unroll
        for (int p = 0; p < 4; ++p) {
            wqf[h].u[p] = pk_bf16(wqp[2*p] * LOG2E, wqp[2*p+1] * LOG2E);
            wkf[h].u[p] = pk_bf16(wkp[2*p],         wkp[2*p+1]);
            wvf[h].u[p] = pk_bf16(wvp[2*p],         wvp[2*p+1]);
        }
        bqv[h] = bq[gh * HD + o] * LOG2E;
        bkv[h] = bk[gh * HD + o];
#pragma unroll
        for (int r = 0; r < 4; ++r)
            bvv[h][r] = bv[gh * HD + 16 * h + 4 * g + r];
    }

    const int lc = blockIdx.x * 64 + 16 * w;
    const int lrow = lc + m;
    const f32x4 zero = {0.f, 0.f, 0.f, 0.f};
    B8 xf;
#pragma unroll
    for (int p = 0; p < 4; ++p) {
        const float a0 = xb[(size_t)(8*g + 2*p)     * LSP + lrow];
        const float a1 = xb[(size_t)(8*g + 2*p + 1) * LSP + lrow];
        xf.u[p] = pk_bf16(a0, a1);
    }
#pragma unroll
    for (int h = 0; h < 2; ++h) {
        f32x4 cq = __builtin_amdgcn_mfma_f32_16x16x32_bf16(xf.h, wqf[h].h, zero, 0, 0, 0);
        f32x4 ck = __builtin_amdgcn_mfma_f32_16x16x32_bf16(xf.h, wkf[h].h, zero, 0, 0, 0);
        f32x4 cv = __builtin_amdgcn_mfma_f32_16x16x32_bf16(wvf[h].h, xf.h, zero, 0, 0, 0);
#pragma unroll
        for (int r = 0; r < 4; ++r) {
            const int lr = lc + 4 * g + r;
            qtb[(size_t)lr * HD + 16 * h + m] = f2bf(cq[r] + bqv[h]);
            ktb[(size_t)lr * HD + 16 * h + m] = f2bf(ck[r] + bkv[h]);
            vb[(size_t)(16 * h + 4 * g + r) * LSP + lc + m] = f2bf(cv[r] + bvv[h][r]);
        }
    }
}

// ---------------- Kernel 2: Z over 64-j block; v *= 1/Z. 512 threads, 8-way k-split ----------------
__global__ __launch_bounds__(512, 4) void z_mfma(
    const short* __restrict__ qt, const short* __restrict__ kt,
    short* __restrict__ v)
{
    const int bg = blockIdx.y;
    const int jb = blockIdx.x * 64;
    const int t = threadIdx.x;
    const int lane = t & 63, w = t >> 6, m = lane & 15, g = lane >> 4;
    const int wq = w & 3, half = w >> 2;

    const short* qtb = qt + (size_t)bg * LSP * HD;
    const short* ktb = kt + (size_t)bg * LSP * HD;
    short* vb = v + (size_t)bg * HD * LSP;

    bf16x8 aq[4];
#pragma unroll
    for (int jq = 0; jq < 4; ++jq)
        aq[jq] = *(const bf16x8*)(qtb + (size_t)(jb + 16 * jq + m) * HD + 8 * g);

    f32x4 zacc[4];
#pragma unroll
    for (int jq = 0; jq < 4; ++jq) zacc[jq] = (f32x4){0.f, 0.f, 0.f, 0.f};

    const f32x4 zero = {0.f, 0.f, 0.f, 0.f};
    // waves 0..3 take even it, 4..7 odd it (it < 49)
    for (int it = half; it < 49; it += 2) {
        const bf16x8 bkc = *(const bf16x8*)(ktb + (size_t)(it * 64 + 16 * wq + m) * HD + 8 * g);
#pragma unroll
        for (int jq = 0; jq < 4; ++jq) {
            f32x4 c = __builtin_amdgcn_mfma_f32_16x16x32_bf16(aq[jq], bkc, zero, 0, 0, 0);
#pragma unroll
            for (int r = 0; r < 4; ++r) zacc[jq][r] += fast_exp2(c[r]);
        }
    }

    __shared__ float zl[64];
    if (t < 64) zl[t] = 0.f;
    __syncthreads();
#pragma unroll
    for (int jq = 0; jq < 4; ++jq) {
#pragma unroll
        for (int r = 0; r < 4; ++r) {
            float s = zacc[jq][r];
            s += __shfl_xor(s, 1); s += __shfl_xor(s, 2);
            s += __shfl_xor(s, 4); s += __shfl_xor(s, 8);
            if (m == 0) atomicAdd(&zl[16 * jq + 4 * g + r], s);
        }
    }
    __syncthreads();

    // scale v rows jb..jb+63: 512 threads -> d = t>>4 (0..31), j-chunk (t&15)*4
    const int d0 = t >> 4;
    const int jl = (t & 15) * 4;
    float rzv[4];
#pragma unroll
    for (int e = 0; e < 4; ++e) rzv[e] = 1.0f / zl[jl + e];
    short* vp = vb + (size_t)d0 * LSP + jb + jl;
    short4v vv = *(short4v*)vp;
    U4 o;
    o.u[0] = pk_bf16(bf2f(vv[0]) * rzv[0], bf2f(vv[1]) * rzv[1]);
    o.u[1] = pk_bf16(bf2f(vv[2]) * rzv[2], bf2f(vv[3]) * rzv[3]);
    *(short4v*)vp = o.h;
}

// ---------------- Kernel 3: out — 64 k-cols/block (R9 tile), 512 threads = 8 waves ----------------
// j-split 8 ways (6-7 iters/wave). 32KB LDS: loop [w][ks2][512]; epilogue 2-level tree.
// All barriers placed per the R10 TBAA lesson (float overwrite of unsigned LDS).
__global__ __launch_bounds__(512, 4) void out_mfma(
    const short* __restrict__ qt, const short* __restrict__ kt,
    const short* __restrict__ v,
    const float* __restrict__ x, float* __restrict__ out)
{
    const int bg = blockIdx.y;
    const int k0 = blockIdx.x * 64;
    const int lane = threadIdx.x & 63, w = threadIdx.x >> 6;
    const int m = lane & 15, g = lane >> 4;

    const short* qtb = qt + (size_t)bg * LSP * HD;
    const short* ktb = kt + (size_t)bg * LSP * HD;
    const short* vb  = v  + (size_t)bg * HD * LSP;

    bf16x8 bk[4];
#pragma unroll
    for (int ks = 0; ks < 4; ++ks)
        bk[ks] = *(const bf16x8*)(ktb + (size_t)(k0 + 16 * ks + m) * HD + 8 * g);

    __shared__ unsigned lds[8192];          // 32KB: loop = 8 waves x 1024; epilogue float[4][2048]
    unsigned* pw = lds + w * 1024;
    const int t2 = 2 * m;
    const int cb = m * 32;

    const f32x4 zero = {0.f, 0.f, 0.f, 0.f};
    f32x4 acc[4][2];
#pragma unroll
    for (int ks = 0; ks < 4; ++ks) { acc[ks][0] = zero; acc[ks][1] = zero; }

    for (int jt = w; jt < 49; jt += 8) {
        const int j0 = jt * 64;

        const bf16x8 av0 = *(const bf16x8*)(vb + (size_t)m        * LSP + j0      + 8 * g);
        const bf16x8 av1 = *(const bf16x8*)(vb + (size_t)m        * LSP + j0 + 32 + 8 * g);
        const bf16x8 av2 = *(const bf16x8*)(vb + (size_t)(16 + m) * LSP + j0      + 8 * g);
        const bf16x8 av3 = *(const bf16x8*)(vb + (size_t)(16 + m) * LSP + j0 + 32 + 8 * g);

        bf16x8 aq[4];
#pragma unroll
        for (int jq = 0; jq < 4; ++jq)
            aq[jq] = *(const bf16x8*)(qtb + (size_t)(j0 + 16 * jq + m) * HD + 8 * g);

        const int blo0 = (4 * g)          ^ t2;
        const int blo1 = (4 * g + 2)      ^ t2;
        const int bhi0 = (16 + 4 * g)     ^ t2;
        const int bhi1 = (16 + 4 * g + 2) ^ t2;

#pragma unroll
        for (int kh = 0; kh < 2; ++kh) {
#pragma unroll
            for (int ks2 = 0; ks2 < 2; ++ks2) {
                const int ks = 2 * kh + ks2;
#pragma unroll
                for (int jq = 0; jq < 4; ++jq) {
                    const f32x4 e = __builtin_amdgcn_mfma_f32_16x16x32_bf16(aq[jq], bk[ks], zero, 0, 0, 0);
                    uint2v w0;
                    w0[0] = pk_bf16(fast_exp2(e[0]), fast_exp2(e[1]));
                    w0[1] = pk_bf16(fast_exp2(e[2]), fast_exp2(e[3]));
                    *(uint2v*)(pw + ks2 * 512 + cb + ((8 * jq + 2 * g) ^ t2)) = w0;
                }
            }
#pragma unroll
            for (int ks2 = 0; ks2 < 2; ++ks2) {
                const int ks = 2 * kh + ks2;
                U8 bplo, bphi;
                bplo.u[0] = *(uint2v*)(pw + ks2 * 512 + cb + blo0);
                bplo.u[1] = *(uint2v*)(pw + ks2 * 512 + cb + blo1);
                bphi.u[0] = *(uint2v*)(pw + ks2 * 512 + cb + bhi0);
                bphi.u[1] = *(uint2v*)(pw + ks2 * 512 + cb + bhi1);
                acc[ks][0] = __builtin_amdgcn_mfma_f32_16x16x32_bf16(av0, bplo.h, acc[ks][0], 0, 0, 0);
                acc[ks][0] = __builtin_amdgcn_mfma_f32_16x16x32_bf16(av1, bphi.h, acc[ks][0], 0, 0, 0);
                acc[ks][1] = __builtin_amdgcn_mfma_f32_16x16x32_bf16(av2, bplo.h, acc[ks][1], 0, 0, 0);
                acc[ks][1] = __builtin_amdgcn_mfma_f32_16x16x32_bf16(av3, bphi.h, acc[ks][1], 0, 0, 0);
            }
        }
    }

    // ---- epilogue: 2-level cross-wave tree over 8 partials ----
    __syncthreads();                        // all P reads done before float overwrite (R10 lesson)
    float* fl = (float*)lds;                // 4 regions x 2048 floats

    if (w >= 4) {                           // level 1: waves 4..7 spill
        const int rw = w - 4;
#pragma unroll
        for (int ks = 0; ks < 4; ++ks)
#pragma unroll
            for (int ds = 0; ds < 2; ++ds)
#pragma unroll
                for (int r = 0; r < 4; ++r) {
                    const int d = 16 * ds + 4 * g + r;
                    fl[rw * 2048 + d * 64 + 16 * ks + m] = acc[ks][ds][r];
                }
    }
    __syncthreads();
    if (w < 4) {                            // level 1: waves 0..3 fold partner in, re-store
#pragma unroll
        for (int ks = 0; ks < 4; ++ks)
#pragma unroll
            for (int ds = 0; ds < 2; ++ds)
#pragma unroll
                for (int r = 0; r < 4; ++r) {
                    const int d = 16 * ds + 4 * g + r;
                    const int a = w * 2048 + d * 64 + 16 * ks + m;
                    fl[a] = acc[ks][ds][r] + fl[a];   // same-wave read->write, in-order
                }
    }
    __syncthreads();

    // level 2: 512 threads, each one f32x4 of the 32d x 64k tile
    const int t = threadIdx.x;
    const int d = t >> 4;                   // 0..31
    const int kloc = (t & 15) * 4;          // 0..60
    f32x4 sv = *(f32x4*)(fl + d * 64 + kloc);
#pragma unroll
    for (int wi = 1; wi < 4; ++wi) {
        const f32x4 a = *(f32x4*)(fl + wi * 2048 + d * 64 + kloc);
#pragma unroll
        for (int r = 0; r < 4; ++r) sv[r] += a[r];
    }
    const size_t idx = (size_t)bg * HD * LSP + (size_t)d * LSP + k0 + kloc;
    const f32x4 xv = *(const f32x4*)(x + idx);
#pragma unroll
    for (int r = 0; r < 4; ++r) sv[r] += xv[r];
    *(f32x4*)(out + idx) = sv;
}

extern "C" void kernel_launch(void* const* d_in, const int* in_sizes, int n_in,
                              void* d_out, int out_size, void* d_ws, size_t ws_size,
                              hipStream_t stream) {
    const float* x  = (const float*)d_in[0];
    const float* Wq = (const float*)d_in[1];
    const float* bq = (const float*)d_in[2];
    const float* Wk = (const float*)d_in[3];
    const float* bk = (const float*)d_in[4];
    const float* Wv = (const float*)d_in[5];
    const float* bv = (const float*)d_in[6];
    float* out = (float*)d_out;

    const size_t QSZ = (size_t)BG * HD * LSP;
    short* qt = (short*)d_ws;
    short* kt = qt + QSZ;
    short* v  = kt + QSZ;

    qkv_mfma<<<dim3(49, BG), 256, 0, stream>>>(x, Wq, bq, Wk, bk, Wv, bv, qt, kt, v);
    z_mfma  <<<dim3(49, BG), 512, 0, stream>>>(qt, kt, v);
    out_mfma<<<dim3(49, BG), 512, 0, stream>>>(qt, kt, v, x, out);
}

// Round 14
// 193.427 us; speedup vs baseline: 1.2445x; 1.0593x over previous
//
#include <hip/hip_runtime.h>

// Problem constants (B=4, C=256, H=W=56, heads=8)
#define NUM_G 8
#define HD    32
#define LSP   3136            // 56*56 = 49*64 exactly
#define BG    32
#define TPB   256
#define LOG2E 1.4426950408889634f

typedef short bf16x8 __attribute__((ext_vector_type(8)));
typedef float f32x4  __attribute__((ext_vector_type(4)));
typedef unsigned uint2v __attribute__((ext_vector_type(2)));
typedef unsigned uint4v __attribute__((ext_vector_type(4)));

union B8 { bf16x8 h; uint4v u; };
union U8 { bf16x8 h; uint2v u[2]; };

// ---- integer-domain 2^x (Schraudolph), replaces trans-pipe v_exp_f32 ----
// bf16 bits of 2^x: u16 = trunc(128*x + (127 - 0.0355)*128 + 0.5)  (rel err +-3.5%)
// pack two: low | high<<16.  2 fma + 2 cvt + 1 shift-or vs 2 v_exp (16+ cyc each).
__device__ __forceinline__ unsigned fast_e2_pk(float a, float b) {
    const int ia = (int)__builtin_fmaf(a, 128.0f, 16251.96f);
    const int ib = (int)__builtin_fmaf(b, 128.0f, 16251.96f);
    return (unsigned)ia | ((unsigned)ib << 16);
}
// f32 value of 2^x, same linear-mantissa approx (consistent with fast_e2_pk)
__device__ __forceinline__ float fast_e2_f32(float x) {
    const int i = (int)__builtin_fmaf(x, 8388608.0f, 1065055420.0f); // (127-0.0355)*2^23
    return __uint_as_float((unsigned)i);
}

__device__ __forceinline__ unsigned pk_bf16(float a, float b) {
#if __has_builtin(__builtin_amdgcn_cvt_pk_bf16_f32)
    typedef __bf16 bf16x2_t __attribute__((ext_vector_type(2)));
    bf16x2_t r = __builtin_amdgcn_cvt_pk_bf16_f32(a, b);
    unsigned u; __builtin_memcpy(&u, &r, 4); return u;
#else
    unsigned ua = __float_as_uint(a); ua += 0x7FFFu + ((ua >> 16) & 1u);
    unsigned ub = __float_as_uint(b); ub += 0x7FFFu + ((ub >> 16) & 1u);
    return (ua >> 16) | (ub & 0xFFFF0000u);
#endif
}

__device__ __forceinline__ short f2bf(float f) {
    unsigned u = __float_as_uint(f);
    u += 0x7FFFu + ((u >> 16) & 1u);
    return (short)(u >> 16);
}

__device__ __forceinline__ float bf2f(short s) {
    return __uint_as_float(((unsigned)(unsigned short)s) << 16);
}

// ---------------- Kernel 1: grouped 1x1 conv via MFMA (R11 form, 1568 blocks) ----------------
__global__ __launch_bounds__(TPB, 4) void qkv_mfma(
    const float* __restrict__ x,
    const float* __restrict__ Wq, const float* __restrict__ bq,
    const float* __restrict__ Wk, const float* __restrict__ bk,
    const float* __restrict__ Wv, const float* __restrict__ bv,
    short* __restrict__ qt, short* __restrict__ kt, short* __restrict__ v)
{
    const int bg = blockIdx.y, gh = bg & (NUM_G - 1);
    const int lane = threadIdx.x & 63, w = threadIdx.x >> 6;
    const int m = lane & 15, g = lane >> 4;

    const float* xb = x + (size_t)bg * HD * LSP;
    short* qtb = qt + (size_t)bg * LSP * HD;
    short* ktb = kt + (size_t)bg * LSP * HD;
    short* vb  = v  + (size_t)bg * HD * LSP;

    B8 wqf[2], wkf[2], wvf[2];
    float bqv[2], bkv[2], bvv[2][4];
#pragma unroll
    for (int h = 0; h < 2; ++h) {
        const int o = 16 * h + m;
        const float* wqp = Wq + (size_t)(gh * HD + o) * HD + 8 * g;
        const float* wkp = Wk + (size_t)(gh * HD + o) * HD + 8 * g;
        const float* wvp = Wv + (size_t)(gh * HD + o) * HD + 8 * g;
#pragma unroll
        for (int p = 0; p < 4; ++p) {
            wqf[h].u[p] = pk_bf16(wqp[2*p] * LOG2E, wqp[2*p+1] * LOG2E);
            wkf[h].u[p] = pk_bf16(wkp[2*p],         wkp[2*p+1]);
            wvf[h].u[p] = pk_bf16(wvp[2*p],         wvp[2*p+1]);
        }
        bqv[h] = bq[gh * HD + o] * LOG2E;
        bkv[h] = bk[gh * HD + o];
#pragma unroll
        for (int r = 0; r < 4; ++r)
            bvv[h][r] = bv[gh * HD + 16 * h + 4 * g + r];
    }

    const int lc = blockIdx.x * 64 + 16 * w;
    const int lrow = lc + m;
    const f32x4 zero = {0.f, 0.f, 0.f, 0.f};
    B8 xf;
#pragma unroll
    for (int p = 0; p < 4; ++p) {
        const float a0 = xb[(size_t)(8*g + 2*p)     * LSP + lrow];
        const float a1 = xb[(size_t)(8*g + 2*p + 1) * LSP + lrow];
        xf.u[p] = pk_bf16(a0, a1);
    }
#pragma unroll
    for (int h = 0; h < 2; ++h) {
        f32x4 cq = __builtin_amdgcn_mfma_f32_16x16x32_bf16(xf.h, wqf[h].h, zero, 0, 0, 0);
        f32x4 ck = __builtin_amdgcn_mfma_f32_16x16x32_bf16(xf.h, wkf[h].h, zero, 0, 0, 0);
        f32x4 cv = __builtin_amdgcn_mfma_f32_16x16x32_bf16(wvf[h].h, xf.h, zero, 0, 0, 0);
#pragma unroll
        for (int r = 0; r < 4; ++r) {
            const int lr = lc + 4 * g + r;
            qtb[(size_t)lr * HD + 16 * h + m] = f2bf(cq[r] + bqv[h]);
            ktb[(size_t)lr * HD + 16 * h + m] = f2bf(ck[r] + bkv[h]);
            vb[(size_t)(16 * h + 4 * g + r) * LSP + lc + m] = f2bf(cv[r] + bvv[h][r]);
        }
    }
}

// ---------------- Kernel 2: Z over 64-j block; v *= 1/Z in-place (R9 form + fast exp) ----------------
__global__ __launch_bounds__(TPB, 6) void z_mfma(
    const short* __restrict__ qt, const short* __restrict__ kt,
    short* __restrict__ v)
{
    const int bg = blockIdx.y;
    const int jb = blockIdx.x * 64;
    const int t = threadIdx.x;
    const int lane = t & 63, w = t >> 6, m = lane & 15, g = lane >> 4;

    const short* qtb = qt + (size_t)bg * LSP * HD;
    const short* ktb = kt + (size_t)bg * LSP * HD;
    short* vb = v + (size_t)bg * HD * LSP;

    bf16x8 aq[4];
#pragma unroll
    for (int jq = 0; jq < 4; ++jq)
        aq[jq] = *(const bf16x8*)(qtb + (size_t)(jb + 16 * jq + m) * HD + 8 * g);

    f32x4 zacc[4];
#pragma unroll
    for (int jq = 0; jq < 4; ++jq) zacc[jq] = (f32x4){0.f, 0.f, 0.f, 0.f};

    const f32x4 zero = {0.f, 0.f, 0.f, 0.f};
    for (int it = 0; it < 49; ++it) {
        const bf16x8 bkc = *(const bf16x8*)(ktb + (size_t)(it * 64 + 16 * w + m) * HD + 8 * g);
#pragma unroll
        for (int jq = 0; jq < 4; ++jq) {
            f32x4 c = __builtin_amdgcn_mfma_f32_16x16x32_bf16(aq[jq], bkc, zero, 0, 0, 0);
#pragma unroll
            for (int r = 0; r < 4; ++r) zacc[jq][r] += fast_e2_f32(c[r]);
        }
    }

    __shared__ float zl[64];
    if (t < 64) zl[t] = 0.f;
    __syncthreads();
#pragma unroll
    for (int jq = 0; jq < 4; ++jq) {
#pragma unroll
        for (int r = 0; r < 4; ++r) {
            float s = zacc[jq][r];
            s += __shfl_xor(s, 1); s += __shfl_xor(s, 2);
            s += __shfl_xor(s, 4); s += __shfl_xor(s, 8);
            if (m == 0) atomicAdd(&zl[16 * jq + 4 * g + r], s);
        }
    }
    __syncthreads();

    const int d0 = t >> 3;
    const int jl = (t & 7) * 8;
    float rzv[8];
#pragma unroll
    for (int e = 0; e < 8; ++e) rzv[e] = 1.0f / zl[jl + e];
    short* vp = vb + (size_t)d0 * LSP + jb + jl;
    bf16x8 vv = *(bf16x8*)vp;
    B8 o;
#pragma unroll
    for (int p = 0; p < 4; ++p)
        o.u[p] = pk_bf16(bf2f(vv[2*p]) * rzv[2*p], bf2f(vv[2*p+1]) * rzv[2*p+1]);
    *(bf16x8*)vp = o.h;
}

// ---------------- Kernel 3: out (R9 form + fast exp) ----------------
__global__ __launch_bounds__(TPB, 4) void out_mfma(
    const short* __restrict__ qt, const short* __restrict__ kt,
    const short* __restrict__ v,
    const float* __restrict__ x, float* __restrict__ out)
{
    const int bg = blockIdx.y;
    const int k0 = blockIdx.x * 64;
    const int lane = threadIdx.x & 63, w = threadIdx.x >> 6;
    const int m = lane & 15, g = lane >> 4;

    const short* qtb = qt + (size_t)bg * LSP * HD;
    const short* ktb = kt + (size_t)bg * LSP * HD;
    const short* vb  = v  + (size_t)bg * HD * LSP;

    bf16x8 bk[4];
#pragma unroll
    for (int ks = 0; ks < 4; ++ks)
        bk[ks] = *(const bf16x8*)(ktb + (size_t)(k0 + 16 * ks + m) * HD + 8 * g);

    __shared__ unsigned lds[4096];          // 16KB: loop = [w][ks2][512]; epilogue float[4][1024]
    unsigned* pw = lds + w * 1024;
    const int t2 = 2 * m;
    const int cb = m * 32;

    const f32x4 zero = {0.f, 0.f, 0.f, 0.f};
    f32x4 acc[4][2];
#pragma unroll
    for (int ks = 0; ks < 4; ++ks) { acc[ks][0] = zero; acc[ks][1] = zero; }

    for (int jt = w; jt < 49; jt += 4) {
        const int j0 = jt * 64;

        const bf16x8 av0 = *(const bf16x8*)(vb + (size_t)m        * LSP + j0      + 8 * g);
        const bf16x8 av1 = *(const bf16x8*)(vb + (size_t)m        * LSP + j0 + 32 + 8 * g);
        const bf16x8 av2 = *(const bf16x8*)(vb + (size_t)(16 + m) * LSP + j0      + 8 * g);
        const bf16x8 av3 = *(const bf16x8*)(vb + (size_t)(16 + m) * LSP + j0 + 32 + 8 * g);

        bf16x8 aq[4];
#pragma unroll
        for (int jq = 0; jq < 4; ++jq)
            aq[jq] = *(const bf16x8*)(qtb + (size_t)(j0 + 16 * jq + m) * HD + 8 * g);

        const int blo0 = (4 * g)          ^ t2;
        const int blo1 = (4 * g + 2)      ^ t2;
        const int bhi0 = (16 + 4 * g)     ^ t2;
        const int bhi1 = (16 + 4 * g + 2) ^ t2;

#pragma unroll
        for (int kh = 0; kh < 2; ++kh) {
#pragma unroll
            for (int ks2 = 0; ks2 < 2; ++ks2) {
                const int ks = 2 * kh + ks2;
#pragma unroll
                for (int jq = 0; jq < 4; ++jq) {
                    const f32x4 e = __builtin_amdgcn_mfma_f32_16x16x32_bf16(aq[jq], bk[ks], zero, 0, 0, 0);
                    uint2v w0;
                    w0[0] = fast_e2_pk(e[0], e[1]);
                    w0[1] = fast_e2_pk(e[2], e[3]);
                    *(uint2v*)(pw + ks2 * 512 + cb + ((8 * jq + 2 * g) ^ t2)) = w0;
                }
            }
#pragma unroll
            for (int ks2 = 0; ks2 < 2; ++ks2) {
                const int ks = 2 * kh + ks2;
                U8 bplo, bphi;
                bplo.u[0] = *(uint2v*)(pw + ks2 * 512 + cb + blo0);
                bplo.u[1] = *(uint2v*)(pw + ks2 * 512 + cb + blo1);
                bphi.u[0] = *(uint2v*)(pw + ks2 * 512 + cb + bhi0);
                bphi.u[1] = *(uint2v*)(pw + ks2 * 512 + cb + bhi1);
                acc[ks][0] = __builtin_amdgcn_mfma_f32_16x16x32_bf16(av0, bplo.h, acc[ks][0], 0, 0, 0);
                acc[ks][0] = __builtin_amdgcn_mfma_f32_16x16x32_bf16(av1, bphi.h, acc[ks][0], 0, 0, 0);
                acc[ks][1] = __builtin_amdgcn_mfma_f32_16x16x32_bf16(av2, bplo.h, acc[ks][1], 0, 0, 0);
                acc[ks][1] = __builtin_amdgcn_mfma_f32_16x16x32_bf16(av3, bphi.h, acc[ks][1], 0, 0, 0);
            }
        }
    }

    // ---- cross-wave reduction, 2 stages of 16KB (32d x 32k per stage) ----
    const int t = threadIdx.x;
    float* fl = (float*)lds;
    const size_t bgb = (size_t)bg * HD * LSP;
#pragma unroll
    for (int s = 0; s < 2; ++s) {
        __syncthreads();                    // barrier before float overwrite of unsigned LDS (R10 lesson)
#pragma unroll
        for (int ks2 = 0; ks2 < 2; ++ks2) {
            const int ks = 2 * s + ks2;
#pragma unroll
            for (int ds = 0; ds < 2; ++ds)
#pragma unroll
                for (int r = 0; r < 4; ++r) {
                    const int d = 16 * ds + 4 * g + r;
                    fl[w * 1024 + d * 32 + 16 * ks2 + m] = acc[ks][ds][r];
                }
        }
        __syncthreads();
        const int d = t >> 3;               // 0..31
        const int kloc = (t & 7) * 4;       // 0..28
        f32x4 sv = *(f32x4*)(fl + d * 32 + kloc);
#pragma unroll
        for (int wi = 1; wi < 4; ++wi) {
            const f32x4 a = *(f32x4*)(fl + wi * 1024 + d * 32 + kloc);
#pragma unroll
            for (int r = 0; r < 4; ++r) sv[r] += a[r];
        }
        const size_t idx = bgb + (size_t)d * LSP + k0 + 32 * s + kloc;
        const f32x4 xv = *(const f32x4*)(x + idx);
#pragma unroll
        for (int r = 0; r < 4; ++r) sv[r] += xv[r];
        *(f32x4*)(out + idx) = sv;
    }
}

extern "C" void kernel_launch(void* const* d_in, const int* in_sizes, int n_in,
                              void* d_out, int out_size, void* d_ws, size_t ws_size,
                              hipStream_t stream) {
    const float* x  = (const float*)d_in[0];
    const float* Wq = (const float*)d_in[1];
    const float* bq = (const float*)d_in[2];
    const float* Wk = (const float*)d_in[3];
    const float* bk = (const float*)d_in[4];
    const float* Wv = (const float*)d_in[5];
    const float* bv = (const float*)d_in[6];
    float* out = (float*)d_out;

    const size_t QSZ = (size_t)BG * HD * LSP;
    short* qt = (short*)d_ws;
    short* kt = qt + QSZ;
    short* v  = kt + QSZ;

    qkv_mfma<<<dim3(49, BG), TPB, 0, stream>>>(x, Wq, bq, Wk, bk, Wv, bv, qt, kt, v);
    z_mfma  <<<dim3(49, BG), TPB, 0, stream>>>(qt, kt, v);
    out_mfma<<<dim3(49, BG), TPB, 0, stream>>>(qt, kt, v, x, out);
}